// Round 1
// baseline (566.317 us; speedup 1.0000x reference)
//
#include <hip/hip_runtime.h>
#include <hip/hip_bf16.h>
#include <math.h>

// Problem constants (B=4, N=4096, C=128)
#define BATCH 4
#define SEQ   4096
#define CDIM  128
#define NROWS (BATCH * SEQ)   // 16384

typedef __attribute__((ext_vector_type(4))) float f32x4;
typedef __attribute__((ext_vector_type(8))) short bf16x8;
typedef __attribute__((ext_vector_type(4))) short bf16x4;

__device__ __forceinline__ short f2bf(float f) {
  unsigned u = __builtin_bit_cast(unsigned, f);
  unsigned r = (u + 0x7FFFu + ((u >> 16) & 1u)) >> 16;  // RNE
  return (short)r;
}
__device__ __forceinline__ float bf2f(short s) {
  unsigned u = ((unsigned)(unsigned short)s) << 16;
  return __builtin_bit_cast(float, u);
}
__device__ __forceinline__ float gelu_exact(float v) {
  return 0.5f * v * (1.0f + erff(v * 0.70710678118654752440f));
}

// ---------------------------------------------------------------------------
// Kernel 0: split the three weight matrices into bf16 hi/lo once.
// Wh/Wl layout: [mat][d][c] row-major, same as W.
// ---------------------------------------------------------------------------
__global__ void wsplit_kernel(const float* __restrict__ Wq,
                              const float* __restrict__ Wk,
                              const float* __restrict__ Wv,
                              short* __restrict__ Wh, short* __restrict__ Wl) {
  int mat = blockIdx.y;
  const float* W = (mat == 0) ? Wq : ((mat == 1) ? Wk : Wv);
  int i = blockIdx.x * 256 + threadIdx.x;  // 0..16383
  float f = W[i];
  short hb = f2bf(f);
  Wh[mat * (CDIM * CDIM) + i] = hb;
  Wl[mat * (CDIM * CDIM) + i] = f2bf(f - bf2f(hb));
}

// ---------------------------------------------------------------------------
// Kernel 1: QKV projection + exact GELU.
//   q[n][d] = gelu(sum_c x[n][c] * W[d][c] + b[d])
// Output: qh/ql, kh/kl as bf16 hi/lo [NROWS][128]; v as bf16 TRANSPOSED
// vT[b][d][n] (so attention PV B-frags are contiguous along n).
// MFMA 16x16x32, split-bf16 (3 terms), no LDS. 4 waves/block, 16 rows/wave.
// ---------------------------------------------------------------------------
__global__ __launch_bounds__(256) void proj_kernel(
    const float* __restrict__ x,
    const short* __restrict__ Wh, const short* __restrict__ Wl,
    const float* __restrict__ bq, const float* __restrict__ bk,
    const float* __restrict__ bv,
    short* __restrict__ qh, short* __restrict__ ql,
    short* __restrict__ kh, short* __restrict__ kl,
    short* __restrict__ vT) {
  const int tid  = threadIdx.x;
  const int wave = tid >> 6;
  const int lane = tid & 63;
  const int g    = lane >> 4;   // lane group 0..3
  const int qr   = lane & 15;   // row/col-in-tile 0..15
  const int row0 = blockIdx.x * 64 + wave * 16;

  // Load + split this wave's 16 x-rows into A-fragments (reused for Q,K,V).
  bf16x8 xh[4], xl[4];
#pragma unroll
  for (int c = 0; c < 4; ++c) {
    const float* px = x + (size_t)(row0 + qr) * CDIM + 8 * g + 32 * c;
    float xv[8];
    *(f32x4*)&xv[0] = *(const f32x4*)px;
    *(f32x4*)&xv[4] = *(const f32x4*)(px + 4);
    bf16x8 h, l;
#pragma unroll
    for (int j = 0; j < 8; ++j) {
      short hb = f2bf(xv[j]);
      h[j] = hb;
      l[j] = f2bf(xv[j] - bf2f(hb));
    }
    xh[c] = h; xl[c] = l;
  }

#pragma unroll
  for (int mat = 0; mat < 3; ++mat) {
    const short* Whm = Wh + mat * (CDIM * CDIM);
    const short* Wlm = Wl + mat * (CDIM * CDIM);
    const float* bias = (mat == 0) ? bq : ((mat == 1) ? bk : bv);

    f32x4 acc[8];
#pragma unroll
    for (int nt = 0; nt < 8; ++nt) acc[nt] = (f32x4){0.f, 0.f, 0.f, 0.f};

#pragma unroll
    for (int nt = 0; nt < 8; ++nt) {
#pragma unroll
      for (int c = 0; c < 4; ++c) {
        // B-frag: B[k][col] = W[col][k]; lane reads W row (16nt+qr), 8 elems.
        const short* pwh = Whm + (size_t)(16 * nt + qr) * CDIM + 8 * g + 32 * c;
        const short* pwl = Wlm + (size_t)(16 * nt + qr) * CDIM + 8 * g + 32 * c;
        bf16x8 whf = *(const bf16x8*)pwh;
        bf16x8 wlf = *(const bf16x8*)pwl;
        acc[nt] = __builtin_amdgcn_mfma_f32_16x16x32_bf16(xh[c], whf, acc[nt], 0, 0, 0);
        acc[nt] = __builtin_amdgcn_mfma_f32_16x16x32_bf16(xl[c], whf, acc[nt], 0, 0, 0);
        acc[nt] = __builtin_amdgcn_mfma_f32_16x16x32_bf16(xh[c], wlf, acc[nt], 0, 0, 0);
      }
    }

    // Epilogue: bias + GELU, split/store.
#pragma unroll
    for (int nt = 0; nt < 8; ++nt) {
      int col = 16 * nt + qr;
      float bi = bias[col];
#pragma unroll
      for (int r = 0; r < 4; ++r) {
        int row = row0 + 4 * g + r;  // D layout: row=(lane>>4)*4+reg
        float gel = gelu_exact(acc[nt][r] + bi);
        if (mat < 2) {
          short hb = f2bf(gel);
          short lb = f2bf(gel - bf2f(hb));
          short* H = (mat == 0) ? qh : kh;
          short* L = (mat == 0) ? ql : kl;
          H[(size_t)row * CDIM + col] = hb;
          L[(size_t)row * CDIM + col] = lb;
        } else {
          int b = row >> 12;        // row / 4096
          int n = row & 4095;
          vT[((size_t)b * CDIM + col) * SEQ + n] = f2bf(gel);
        }
      }
    }
  }
}

// ---------------------------------------------------------------------------
// Kernel 2: flash attention, one 16-row Q tile per block, 4 waves splitting
// the 4096 KV rows 4 ways (1024 each), merged at the end via LDS.
// QK^T swapped (S^T = K·Q^T) so S^T D-registers ARE the PV A-fragment.
// ---------------------------------------------------------------------------
__global__ __launch_bounds__(256) void attn_kernel(
    const short* __restrict__ qh, const short* __restrict__ ql,
    const short* __restrict__ kh, const short* __restrict__ kl,
    const short* __restrict__ vT, float* __restrict__ out) {
  __shared__ float s_acc[4][64][33];   // padded: stride 33 -> conflict-free
  __shared__ float s_ml[4][2][16];

  const int tid  = threadIdx.x;
  const int wave = tid >> 6;
  const int lane = tid & 63;
  const int g    = lane >> 4;
  const int qr   = lane & 15;

  const int b  = blockIdx.x >> 8;      // 256 q-tiles per batch
  const int qt = blockIdx.x & 255;
  const size_t qrow = (size_t)b * SEQ + qt * 16;

  // Q B-fragments (hi/lo): lane holds Q[qr][8g+j+32c]
  bf16x8 qhf[4], qlf[4];
#pragma unroll
  for (int c = 0; c < 4; ++c) {
    qhf[c] = *(const bf16x8*)(qh + (qrow + qr) * CDIM + 8 * g + 32 * c);
    qlf[c] = *(const bf16x8*)(ql + (qrow + qr) * CDIM + 8 * g + 32 * c);
  }

  f32x4 acc[8];
#pragma unroll
  for (int dt = 0; dt < 8; ++dt) acc[dt] = (f32x4){0.f, 0.f, 0.f, 0.f};
  float m = -INFINITY, lsum = 0.f;

  const int kvbase = wave * (SEQ / 4);          // 1024 KV rows per wave
  const short* vTb = vT + (size_t)b * CDIM * SEQ;

  for (int it = 0; it < (SEQ / 4) / 32; ++it) { // 32 iterations of KVBLK=32
    const int kbase = kvbase + it * 32;
    const size_t krow = (size_t)b * SEQ + kbase;

    // ---- S^T = K·Q^T for two 16-row subtiles (split-bf16: 3 MFMAs/chunk) --
    f32x4 sA[2];
#pragma unroll
    for (int s = 0; s < 2; ++s) {
      const short* kbh = kh + (krow + 16 * s + qr) * CDIM;
      const short* kbl = kl + (krow + 16 * s + qr) * CDIM;
      f32x4 sc[4];
#pragma unroll
      for (int c = 0; c < 4; ++c) {             // 4 independent chains
        bf16x8 khf = *(const bf16x8*)(kbh + 8 * g + 32 * c);
        bf16x8 klf = *(const bf16x8*)(kbl + 8 * g + 32 * c);
        f32x4 t = (f32x4){0.f, 0.f, 0.f, 0.f};
        t = __builtin_amdgcn_mfma_f32_16x16x32_bf16(khf, qhf[c], t, 0, 0, 0);
        t = __builtin_amdgcn_mfma_f32_16x16x32_bf16(khf, qlf[c], t, 0, 0, 0);
        t = __builtin_amdgcn_mfma_f32_16x16x32_bf16(klf, qhf[c], t, 0, 0, 0);
        sc[c] = t;
      }
      sA[s] = (sc[0] + sc[1]) + (sc[2] + sc[3]);
    }
    // lane now holds S[k = kbase+16s+4g+r][q = qr] for s=0,1; r=0..3

    // ---- online softmax (per q-row = qr, replicated across g groups) ------
    float tm = fmaxf(fmaxf(fmaxf(sA[0][0], sA[0][1]), fmaxf(sA[0][2], sA[0][3])),
                     fmaxf(fmaxf(sA[1][0], sA[1][1]), fmaxf(sA[1][2], sA[1][3])));
    tm = fmaxf(tm, __shfl_xor(tm, 16, 64));
    tm = fmaxf(tm, __shfl_xor(tm, 32, 64));
    float mnew  = fmaxf(m, tm);
    float alpha = __expf(m - mnew);             // first iter: exp(-inf)=0
    float p[8];
    float ps = 0.f;
#pragma unroll
    for (int s = 0; s < 2; ++s)
#pragma unroll
      for (int r = 0; r < 4; ++r) {
        float e = __expf(sA[s][r] - mnew);
        p[s * 4 + r] = e;
        ps += e;
      }
    ps += __shfl_xor(ps, 16, 64);
    ps += __shfl_xor(ps, 32, 64);
    lsum = lsum * alpha + ps;
    m = mnew;

    // P fragments: lane holds P[qr][4g+j] == A-frag of mfma_16x16x16
    bf16x4 pf0, pf1;
#pragma unroll
    for (int r = 0; r < 4; ++r) { pf0[r] = f2bf(p[r]); pf1[r] = f2bf(p[4 + r]); }

    // Rescale accumulator: PV layout rows are q = 4g+r -> fetch alpha by shfl
    float af[4];
#pragma unroll
    for (int r = 0; r < 4; ++r) af[r] = __shfl(alpha, 4 * g + r, 64);
#pragma unroll
    for (int dt = 0; dt < 8; ++dt)
#pragma unroll
      for (int r = 0; r < 4; ++r) acc[dt][r] *= af[r];

    // ---- PV: B-frag = V[k][d] = vT[d][k], 4 contiguous bf16 along n -------
#pragma unroll
    for (int dt = 0; dt < 8; ++dt) {
      const short* vrow = vTb + (size_t)(16 * dt + qr) * SEQ + kbase;
      bf16x4 v0 = *(const bf16x4*)(vrow + 4 * g);
      bf16x4 v1 = *(const bf16x4*)(vrow + 16 + 4 * g);
      acc[dt] = __builtin_amdgcn_mfma_f32_16x16x16bf16_1k(pf0, v0, acc[dt], 0, 0, 0);
      acc[dt] = __builtin_amdgcn_mfma_f32_16x16x16bf16_1k(pf1, v1, acc[dt], 0, 0, 0);
    }
  }

  // ---- merge the 4 KV-split partials --------------------------------------
#pragma unroll
  for (int dt = 0; dt < 8; ++dt)
#pragma unroll
    for (int r = 0; r < 4; ++r) s_acc[wave][lane][dt * 4 + r] = acc[dt][r];
  if (lane < 16) { s_ml[wave][0][lane] = m; s_ml[wave][1][lane] = lsum; }
  __syncthreads();

  float beta0[4], beta1[4], beta2[4], beta3[4], linv[4];
#pragma unroll
  for (int r = 0; r < 4; ++r) {
    int q = 4 * g + r;
    float m0 = s_ml[0][0][q], m1 = s_ml[1][0][q];
    float m2 = s_ml[2][0][q], m3 = s_ml[3][0][q];
    float ms = fmaxf(fmaxf(m0, m1), fmaxf(m2, m3));
    float b0 = __expf(m0 - ms), b1 = __expf(m1 - ms);
    float b2 = __expf(m2 - ms), b3 = __expf(m3 - ms);
    float ls = s_ml[0][1][q] * b0 + s_ml[1][1][q] * b1 +
               s_ml[2][1][q] * b2 + s_ml[3][1][q] * b3;
    beta0[r] = b0; beta1[r] = b1; beta2[r] = b2; beta3[r] = b3;
    linv[r] = 1.0f / ls;
  }

  // wave w finalizes d-tiles {2w, 2w+1}
#pragma unroll
  for (int dtt = 0; dtt < 2; ++dtt) {
    int dt = 2 * wave + dtt;
#pragma unroll
    for (int r = 0; r < 4; ++r) {
      float v = s_acc[0][lane][dt * 4 + r] * beta0[r] +
                s_acc[1][lane][dt * 4 + r] * beta1[r] +
                s_acc[2][lane][dt * 4 + r] * beta2[r] +
                s_acc[3][lane][dt * 4 + r] * beta3[r];
      out[(qrow + 4 * g + r) * CDIM + 16 * dt + qr] = v * linv[r];
    }
  }
}

// ---------------------------------------------------------------------------
extern "C" void kernel_launch(void* const* d_in, const int* in_sizes, int n_in,
                              void* d_out, int out_size, void* d_ws, size_t ws_size,
                              hipStream_t stream) {
  const float* x  = (const float*)d_in[0];
  const float* Wq = (const float*)d_in[1];
  const float* bq = (const float*)d_in[2];
  const float* Wk = (const float*)d_in[3];
  const float* bk = (const float*)d_in[4];
  const float* Wv = (const float*)d_in[5];
  const float* bv = (const float*)d_in[6];
  float* out = (float*)d_out;

  // Workspace layout (bf16 = short). Needs ~20.2 MB.
  char* ws = (char*)d_ws;
  const size_t NB = (size_t)NROWS * CDIM * sizeof(short);  // 4 MB per buffer
  short* qh = (short*)(ws);
  short* ql = (short*)(ws + 1 * NB);
  short* kh = (short*)(ws + 2 * NB);
  short* kl = (short*)(ws + 3 * NB);
  short* vT = (short*)(ws + 4 * NB);
  short* Wh = (short*)(ws + 5 * NB);
  short* Wl = (short*)(ws + 5 * NB + 3 * CDIM * CDIM * sizeof(short));

  wsplit_kernel<<<dim3(CDIM * CDIM / 256, 3), 256, 0, stream>>>(Wq, Wk, Wv, Wh, Wl);
  proj_kernel<<<NROWS / 64, 256, 0, stream>>>(x, Wh, Wl, bq, bk, bv,
                                              qh, ql, kh, kl, vT);
  attn_kernel<<<BATCH * (SEQ / 16), 256, 0, stream>>>(qh, ql, kh, kl, vT, out);
}

// Round 2
// 194.245 us; speedup vs baseline: 2.9155x; 2.9155x over previous
//
#include <hip/hip_runtime.h>
#include <hip/hip_bf16.h>
#include <math.h>

// Problem constants (B=4, N=4096, C=128)
#define BATCH 4
#define SEQ   4096
#define CDIM  128
#define NROWS (BATCH * SEQ)        // 16384
#define KVB   32                   // KV rows per tile
#define NTILE (SEQ / KVB)          // 128 tiles per batch
#define KTILE_B 8192               // K tile image bytes (32 x 128 fp16, swizzled)
#define VSTRIDE 48                 // halfwords per d-row of V tile image (32 + 16 pad)
#define VTILE_B (CDIM * VSTRIDE * 2)  // 12288 bytes (transposed [d][k] bf16, padded)
#define STAGE_B (KTILE_B + VTILE_B)   // 20480 bytes per KV tile

typedef __attribute__((ext_vector_type(4))) float    f32x4;
typedef __attribute__((ext_vector_type(8))) _Float16 half8;
typedef __attribute__((ext_vector_type(4))) short    bf16x4;

__device__ __forceinline__ short f2bf(float f) {
  unsigned u = __builtin_bit_cast(unsigned, f);
  unsigned r = (u + 0x7FFFu + ((u >> 16) & 1u)) >> 16;  // RNE
  return (short)r;
}
__device__ __forceinline__ float gelu_exact(float v) {
  return 0.5f * v * (1.0f + erff(v * 0.70710678118654752440f));
}

// K tile image swizzle: row r (0..31), feature c (0..127) -> byte offset in 8KB tile.
// 16B slot index (c>>3) gets its low 3 bits XOR'd with row, so the attn wave's
// ds_read_b128 (lanes span 16 rows x 4 slots) spreads evenly over all banks.
__device__ __forceinline__ int kswz(int r, int c) {
  int slot  = c >> 3;
  int slotp = (slot & 8) | ((slot ^ r) & 7);
  return r * 256 + slotp * 16 + (c & 7) * 2;
}

__device__ __forceinline__ void gl_lds16(const void* g, void* l) {
  __builtin_amdgcn_global_load_lds(
      (const __attribute__((address_space(1))) void*)g,
      (__attribute__((address_space(3))) void*)l, 16, 0, 0);
}

// ---------------------------------------------------------------------------
// Kernel 0: W -> fp16 fragment layout. wfrag[mat][nt][cc][lane][8]
// ---------------------------------------------------------------------------
__global__ void wprep_kernel(const float* __restrict__ Wq,
                             const float* __restrict__ Wk,
                             const float* __restrict__ Wv,
                             _Float16* __restrict__ wfrag) {
  int mat = blockIdx.y;
  const float* W = (mat == 0) ? Wq : ((mat == 1) ? Wk : Wv);
  int i = blockIdx.x * 256 + threadIdx.x;   // 0..16383
  int d = i >> 7, c = i & 127;
  int nt = d >> 4, qr = d & 15, cc = c >> 5, g = (c >> 3) & 3, j = c & 7;
  wfrag[(size_t)((((mat * 8 + nt) * 4 + cc) * 64) + 16 * g + qr) * 8 + j] =
      (_Float16)W[i];
}

// ---------------------------------------------------------------------------
// Kernel 1: QKV projection + exact GELU (fp16 MFMA).
// Outputs: qfrag (fp16 fragment layout), kimg (fp16 swizzled tile images),
// vimg (bf16 transposed padded tile images).
// ---------------------------------------------------------------------------
__global__ __launch_bounds__(256) void proj_kernel(
    const float* __restrict__ x, const _Float16* __restrict__ wfrag,
    const float* __restrict__ bq, const float* __restrict__ bk,
    const float* __restrict__ bv,
    _Float16* __restrict__ qfrag, _Float16* __restrict__ kimg,
    short* __restrict__ vimg) {
  const int tid = threadIdx.x, wave = tid >> 6, lane = tid & 63;
  const int g = lane >> 4, qr = lane & 15;
  const int row0 = blockIdx.x * 64 + wave * 16;

  // x rows as fp16 A-fragments: A[row=l&15][k = 8*(l>>4)+j+32c]
  half8 xf[4];
#pragma unroll
  for (int c4 = 0; c4 < 4; ++c4) {
    const float* px = x + (size_t)(row0 + qr) * CDIM + 8 * g + 32 * c4;
    f32x4 a = *(const f32x4*)px;
    f32x4 bvec = *(const f32x4*)(px + 4);
    half8 hx;
#pragma unroll
    for (int j = 0; j < 4; ++j) { hx[j] = (_Float16)a[j]; hx[4 + j] = (_Float16)bvec[j]; }
    xf[c4] = hx;
  }

#pragma unroll
  for (int mat = 0; mat < 3; ++mat) {
    const float* bias = (mat == 0) ? bq : ((mat == 1) ? bk : bv);
    f32x4 acc[8];
#pragma unroll
    for (int nt = 0; nt < 8; ++nt) acc[nt] = (f32x4){0.f, 0.f, 0.f, 0.f};
#pragma unroll
    for (int nt = 0; nt < 8; ++nt) {
#pragma unroll
      for (int c4 = 0; c4 < 4; ++c4) {
        half8 wf = *(const half8*)(wfrag +
            ((size_t)(((mat * 8 + nt) * 4 + c4) * 64) + lane) * 8);
        acc[nt] = __builtin_amdgcn_mfma_f32_16x16x32_f16(xf[c4], wf, acc[nt], 0, 0, 0);
      }
    }
#pragma unroll
    for (int nt = 0; nt < 8; ++nt) {
      int col = 16 * nt + qr;
      float bi = bias[col];
#pragma unroll
      for (int r = 0; r < 4; ++r) {
        int row = row0 + 4 * g + r;   // D layout: row=(lane>>4)*4+reg, col=lane&15
        float val = gelu_exact(acc[nt][r] + bi);
        if (mat == 0) {
          int t = row >> 4;
          int lane2 = ((col >> 3) & 3) * 16 + (row & 15);
          qfrag[((size_t)(t * 4 + (col >> 5)) * 64 + lane2) * 8 + (col & 7)] =
              (_Float16)val;
        } else if (mat == 1) {
          int b_ = row >> 12, nn = row & 4095;
          size_t tile = (size_t)b_ * NTILE + (nn >> 5);
          *(_Float16*)((char*)kimg + tile * KTILE_B + kswz(nn & 31, col)) =
              (_Float16)val;
        } else {
          int b_ = row >> 12, nn = row & 4095;
          size_t tile = (size_t)b_ * NTILE + (nn >> 5);
          vimg[tile * (CDIM * VSTRIDE) + (size_t)col * VSTRIDE + (nn & 31)] =
              f2bf(val);
        }
      }
    }
  }
}

// ---------------------------------------------------------------------------
// Kernel 2: flash attention. Block = 4 waves, each wave owns a DIFFERENT
// 16-row Q tile (Q-tile 64/block); all waves share LDS-staged KV tiles.
// KV split 2-way across blocks (partials combined by kernel 3).
// Double-buffered global_load_lds staging, 2-phase vmcnt(0)+barrier loop.
// ---------------------------------------------------------------------------
__global__ __launch_bounds__(256) void attn_kernel(
    const _Float16* __restrict__ qfrag, const _Float16* __restrict__ kimg,
    const short* __restrict__ vimg, float* __restrict__ pacc,
    float* __restrict__ pml) {
  __shared__ __align__(16) char smem[2 * STAGE_B];   // 40 KB
  const int tid = threadIdx.x, wave = tid >> 6, lane = tid & 63;
  const int g = lane >> 4, qr = lane & 15;

  // XCD grouping: blocks with equal (i&7) share an XCD's L2 -> give them the
  // same (batch, kv-half) so the 1.1MB KV stream is L2-resident.
  const int i = blockIdx.x;
  const int b = (i >> 1) & 3, h = i & 1, qb = i >> 3;

  // Q fragments (B-operand of S^T = K.Q^T): coalesced from fragment layout.
  half8 qf[4];
  const int t = b * 256 + qb * 4 + wave;
#pragma unroll
  for (int c = 0; c < 4; ++c)
    qf[c] = *(const half8*)(qfrag + ((size_t)(t * 4 + c) * 64 + lane) * 8);

  const char* kbase = (const char*)kimg + ((size_t)b * NTILE + h * (NTILE / 2)) * KTILE_B;
  const char* vbase = (const char*)vimg + ((size_t)b * NTILE + h * (NTILE / 2)) * VTILE_B;

  auto stage = [&](int it, char* buf) {
    const char* ks = kbase + (size_t)it * KTILE_B;
    const char* vs = vbase + (size_t)it * VTILE_B;
#pragma unroll
    for (int p = 0; p < 2; ++p)                       // 8 KB K image
      gl_lds16(ks + (tid + 256 * p) * 16, buf + (tid + 256 * p) * 16);
#pragma unroll
    for (int p = 0; p < 3; ++p)                       // 12 KB V image
      gl_lds16(vs + (tid + 256 * p) * 16, buf + KTILE_B + (tid + 256 * p) * 16);
  };

  f32x4 acc[8];
#pragma unroll
  for (int dt = 0; dt < 8; ++dt) acc[dt] = (f32x4){0.f, 0.f, 0.f, 0.f};
  float m = -INFINITY, lsum = 0.f;

  stage(0, smem);
  const int NT = NTILE / 2;   // 64 tiles per block
  for (int X = 0; X < NT; ++X) {
    // stage(X) done (vmcnt) + everyone finished reading the buffer we are
    // about to overwrite (lgkmcnt + barrier).
    asm volatile("s_waitcnt vmcnt(0) lgkmcnt(0)" ::: "memory");
    __builtin_amdgcn_s_barrier();
    if (X + 1 < NT) stage(X + 1, smem + ((X + 1) & 1) * STAGE_B);

    const char* kb = smem + (X & 1) * STAGE_B;
    const char* vb = kb + KTILE_B;

    // K A-fragments from swizzled LDS image
    half8 kf[2][4];
#pragma unroll
    for (int s = 0; s < 2; ++s)
#pragma unroll
      for (int c4 = 0; c4 < 4; ++c4) {
        int slot = 4 * c4 + g;
        int slotp = (slot & 8) | ((slot ^ qr) & 7);
        kf[s][c4] = *(const half8*)(kb + (16 * s + qr) * 256 + slotp * 16);
      }
    // V B-fragments from transposed padded LDS image (independent of softmax)
    bf16x4 vf[8][2];
#pragma unroll
    for (int dt = 0; dt < 8; ++dt)
#pragma unroll
      for (int s2 = 0; s2 < 2; ++s2)
        vf[dt][s2] = *(const bf16x4*)(vb + (16 * dt + qr) * (VSTRIDE * 2) +
                                      (16 * s2 + 4 * g) * 2);

    // S^T = K.Q^T : lane holds S[k=16s+4g+r][q=qr]
    f32x4 sA[2];
#pragma unroll
    for (int s = 0; s < 2; ++s) {
      f32x4 tacc = (f32x4){0.f, 0.f, 0.f, 0.f};
#pragma unroll
      for (int c4 = 0; c4 < 4; ++c4)
        tacc = __builtin_amdgcn_mfma_f32_16x16x32_f16(kf[s][c4], qf[c4], tacc, 0, 0, 0);
      sA[s] = tacc;
    }

    // online softmax per q-row (= qr), replicated across the 4 g-groups
    float tm = fmaxf(fmaxf(fmaxf(sA[0][0], sA[0][1]), fmaxf(sA[0][2], sA[0][3])),
                     fmaxf(fmaxf(sA[1][0], sA[1][1]), fmaxf(sA[1][2], sA[1][3])));
    tm = fmaxf(tm, __shfl_xor(tm, 16, 64));
    tm = fmaxf(tm, __shfl_xor(tm, 32, 64));

    bool defer = __all(tm <= m + 8.0f);            // T13 defer-max, THR=8
    float mn = defer ? m : fmaxf(m, tm);
    float p[8];
    float ps = 0.f;
#pragma unroll
    for (int e = 0; e < 8; ++e) {
      p[e] = __expf(sA[e >> 2][e & 3] - mn);
      ps += p[e];
    }
    ps += __shfl_xor(ps, 16, 64);
    ps += __shfl_xor(ps, 32, 64);
    if (defer) {
      lsum += ps;
    } else {
      float alpha = __expf(m - mn);
      lsum = lsum * alpha + ps;
      m = mn;
      float af[4];
#pragma unroll
      for (int r = 0; r < 4; ++r) af[r] = __shfl(alpha, 4 * g + r, 64);
#pragma unroll
      for (int dt = 0; dt < 8; ++dt)
#pragma unroll
        for (int r = 0; r < 4; ++r) acc[dt][r] *= af[r];
    }

    // P fragments: lane holds P[qr][16s+4g+r] == A-frag of mfma_16x16x16
    bf16x4 pf0, pf1;
#pragma unroll
    for (int r = 0; r < 4; ++r) { pf0[r] = f2bf(p[r]); pf1[r] = f2bf(p[4 + r]); }
#pragma unroll
    for (int dt = 0; dt < 8; ++dt) {
      acc[dt] = __builtin_amdgcn_mfma_f32_16x16x16bf16_1k(pf0, vf[dt][0], acc[dt], 0, 0, 0);
      acc[dt] = __builtin_amdgcn_mfma_f32_16x16x16bf16_1k(pf1, vf[dt][1], acc[dt], 0, 0, 0);
    }
  }

  // Partials (flash combine happens in combine_kernel)
  const int growbase = b * SEQ + qb * 64 + wave * 16;
#pragma unroll
  for (int dt = 0; dt < 8; ++dt)
#pragma unroll
    for (int r = 0; r < 4; ++r) {
      int grow = growbase + 4 * g + r;
      pacc[((size_t)h * NROWS + grow) * CDIM + 16 * dt + qr] = acc[dt][r];
    }
  if (lane < 16) {
    int grow = growbase + qr;
    pml[((size_t)h * NROWS + grow) * 2 + 0] = m;
    pml[((size_t)h * NROWS + grow) * 2 + 1] = lsum;
  }
}

// ---------------------------------------------------------------------------
// Kernel 3: combine the two KV-half partials.
// ---------------------------------------------------------------------------
__global__ __launch_bounds__(256) void combine_kernel(
    const float* __restrict__ pacc, const float* __restrict__ pml,
    float* __restrict__ out) {
  int idx = blockIdx.x * 256 + threadIdx.x;   // 0 .. NROWS*32-1
  int row = idx >> 5, d4 = idx & 31;
  float m0 = pml[(size_t)row * 2 + 0], l0 = pml[(size_t)row * 2 + 1];
  float m1 = pml[((size_t)NROWS + row) * 2 + 0], l1 = pml[((size_t)NROWS + row) * 2 + 1];
  float M = fmaxf(m0, m1);
  float e0 = __expf(m0 - M), e1 = __expf(m1 - M);
  float inv = 1.0f / (l0 * e0 + l1 * e1);
  f32x4 a0 = ((const f32x4*)pacc)[(size_t)row * 32 + d4];
  f32x4 a1 = ((const f32x4*)pacc)[((size_t)NROWS + row) * 32 + d4];
  f32x4 v = (a0 * e0 + a1 * e1) * inv;
  ((f32x4*)out)[(size_t)row * 32 + d4] = v;
}

// ---------------------------------------------------------------------------
extern "C" void kernel_launch(void* const* d_in, const int* in_sizes, int n_in,
                              void* d_out, int out_size, void* d_ws, size_t ws_size,
                              hipStream_t stream) {
  const float* x  = (const float*)d_in[0];
  const float* Wq = (const float*)d_in[1];
  const float* bq = (const float*)d_in[2];
  const float* Wk = (const float*)d_in[3];
  const float* bk = (const float*)d_in[4];
  const float* Wv = (const float*)d_in[5];
  const float* bv = (const float*)d_in[6];
  float* out = (float*)d_out;

  // Workspace layout (~30.4 MB)
  char* ws = (char*)d_ws;
  _Float16* qfrag = (_Float16*)(ws);                                  // 4 MB
  _Float16* kimg  = (_Float16*)(ws + 4194304);                        // 4 MB
  short*    vimg  = (short*)(ws + 8388608);                           // 6 MB
  _Float16* wfrag = (_Float16*)(ws + 14680064);                       // 96 KB
  float*    pacc  = (float*)(ws + 14778368);                          // 16 MB
  float*    pml   = (float*)(ws + 31555584);                          // 256 KB

  wprep_kernel<<<dim3(64, 3), 256, 0, stream>>>(Wq, Wk, Wv, wfrag);
  proj_kernel<<<NROWS / 64, 256, 0, stream>>>(x, wfrag, bq, bk, bv,
                                              qfrag, kimg, vimg);
  attn_kernel<<<512, 256, 0, stream>>>(qfrag, kimg, vimg, pacc, pml);
  combine_kernel<<<NROWS * 32 / 256, 256, 0, stream>>>(pacc, pml, out);
}

// Round 4
// 162.596 us; speedup vs baseline: 3.4830x; 1.1946x over previous
//
#include <hip/hip_runtime.h>
#include <hip/hip_bf16.h>
#include <math.h>

// Problem constants (B=4, N=4096, C=128)
#define BATCH 4
#define SEQ   4096
#define CDIM  128
#define NROWS (BATCH * SEQ)        // 16384
#define KVB   32                   // KV rows per tile
#define NTILE (SEQ / KVB)          // 128 tiles per batch
#define KTILE_B 8192               // K tile: 32 x 128 fp16, swizzled
#define VTILE_B 8192               // V tile: [(k>>2)][d][k&3] bf16
#define STAGE_B (KTILE_B + VTILE_B)   // 16 KB per KV tile
#define LOG2E 1.4426950408889634f

typedef __attribute__((ext_vector_type(4))) float    f32x4;
typedef __attribute__((ext_vector_type(8))) _Float16 half8;
typedef __attribute__((ext_vector_type(4))) short    bf16x4;
typedef __attribute__((ext_vector_type(8))) short    bf16x8;

__device__ __forceinline__ float bf2f(short s) {
  unsigned u = ((unsigned)(unsigned short)s) << 16;
  return __builtin_bit_cast(float, u);
}
__device__ __forceinline__ short f2bf(float f) {   // native cvt (compiler picks pk form)
  __hip_bfloat16 h = __float2bfloat16(f);
  return __builtin_bit_cast(short, h);
}
__device__ __forceinline__ float gelu_exact(float v) {
  return 0.5f * v * (1.0f + erff(v * 0.70710678118654752440f));
}
// K tile swizzle (halfword offset within 4096-halfword tile image).
__device__ __forceinline__ int kswz_h(int r, int c) {
  int slot  = c >> 3;
  int slotp = (slot & 8) | ((slot ^ r) & 7);
  return r * 128 + slotp * 8 + (c & 7);
}
__device__ __forceinline__ void gl_lds16(const void* g, void* l) {
  __builtin_amdgcn_global_load_lds(
      (const __attribute__((address_space(1))) void*)g,
      (__attribute__((address_space(3))) void*)l, 16, 0, 0);
}

// ---------------------------------------------------------------------------
// Kernel 0: W -> fp16 fragment layout. wfrag[mat][nt][cc][lane][8]
// ---------------------------------------------------------------------------
__global__ void wprep_kernel(const float* __restrict__ Wq,
                             const float* __restrict__ Wk,
                             const float* __restrict__ Wv,
                             _Float16* __restrict__ wfrag) {
  int mat = blockIdx.y;
  const float* W = (mat == 0) ? Wq : ((mat == 1) ? Wk : Wv);
  int i = blockIdx.x * 256 + threadIdx.x;   // 0..16383
  int d = i >> 7, c = i & 127;
  int nt = d >> 4, qr = d & 15, cc = c >> 5, g = (c >> 3) & 3, j = c & 7;
  wfrag[(size_t)((((mat * 8 + nt) * 4 + cc) * 64) + 16 * g + qr) * 8 + j] =
      (_Float16)W[i];
}

// ---------------------------------------------------------------------------
// Kernel 1: QKV projection + exact GELU (fp16 MFMA), outputs bounced through
// LDS so all global stores are coalesced 16B. Q is pre-scaled by log2e.
// ---------------------------------------------------------------------------
__global__ __launch_bounds__(256) void proj_kernel(
    const float* __restrict__ x, const _Float16* __restrict__ wfrag,
    const float* __restrict__ bq, const float* __restrict__ bk,
    const float* __restrict__ bv,
    _Float16* __restrict__ qfrag, _Float16* __restrict__ kimg,
    short* __restrict__ vimg) {
  __shared__ __align__(16) char pls[16384];
  const int tid = threadIdx.x, wave = tid >> 6, lane = tid & 63;
  const int g = lane >> 4, qr = lane & 15;
  const int row0 = blockIdx.x * 64 + wave * 16;

  // x rows as fp16 A-fragments: A[row=l&15][k = 8*(l>>4)+j+32c]
  half8 xf[4];
#pragma unroll
  for (int c4 = 0; c4 < 4; ++c4) {
    const float* px = x + (size_t)(row0 + qr) * CDIM + 8 * g + 32 * c4;
    f32x4 a = *(const f32x4*)px;
    f32x4 bb = *(const f32x4*)(px + 4);
    half8 hx;
#pragma unroll
    for (int j = 0; j < 4; ++j) { hx[j] = (_Float16)a[j]; hx[4 + j] = (_Float16)bb[j]; }
    xf[c4] = hx;
  }

#pragma unroll
  for (int mat = 0; mat < 3; ++mat) {
    const float* bias = (mat == 0) ? bq : ((mat == 1) ? bk : bv);
    f32x4 acc[8];
#pragma unroll
    for (int nt = 0; nt < 8; ++nt) acc[nt] = (f32x4){0.f, 0.f, 0.f, 0.f};
#pragma unroll
    for (int nt = 0; nt < 8; ++nt)
#pragma unroll
      for (int c4 = 0; c4 < 4; ++c4) {
        half8 wf = *(const half8*)(wfrag +
            ((size_t)(((mat * 8 + nt) * 4 + c4) * 64) + lane) * 8);
        acc[nt] = __builtin_amdgcn_mfma_f32_16x16x32_f16(xf[c4], wf, acc[nt], 0, 0, 0);
      }

    // Scatter epilogue into LDS (2B), then coalesced dump.
    short* ls = (short*)pls;
#pragma unroll
    for (int nt = 0; nt < 8; ++nt) {
      int col = 16 * nt + qr;
      float bi = bias[col];
#pragma unroll
      for (int r = 0; r < 4; ++r) {
        int rl = wave * 16 + 4 * g + r;        // row within block (0..63)
        float val = gelu_exact(acc[nt][r] + bi);
        int off;
        short sv;
        if (mat == 0) {
          // Q-frag: [t_local(=wave)][c4][lane2][j], scaled by log2e
          int lane2 = ((col >> 3) & 3) * 16 + (rl & 15);
          off = ((wave * 4 + (col >> 5)) * 64 + lane2) * 8 + (col & 7);
          sv = __builtin_bit_cast(short, (_Float16)(val * LOG2E));
        } else if (mat == 1) {
          int tl = rl >> 5, rr = rl & 31;
          off = tl * 4096 + kswz_h(rr, col);
          sv = __builtin_bit_cast(short, (_Float16)val);
        } else {
          int tl = rl >> 5, rr = rl & 31;
          off = tl * 4096 + ((rr >> 2) * 128 + col) * 4 + (rr & 3);
          sv = f2bf(val);
        }
        ls[off] = sv;
      }
    }
    __syncthreads();
    char* gdst = (mat == 0) ? (char*)qfrag + (size_t)blockIdx.x * 16384
               : (mat == 1) ? (char*)kimg + (size_t)blockIdx.x * 16384
                            : (char*)vimg + (size_t)blockIdx.x * 16384;
#pragma unroll
    for (int p = 0; p < 4; ++p)
      ((f32x4*)gdst)[tid + 256 * p] = ((const f32x4*)pls)[tid + 256 * p];
    __syncthreads();
  }
}

// ---------------------------------------------------------------------------
// Kernel 2: flash attention. Block = 4 waves x 32 Q-rows (2 Q-tiles/wave),
// shared LDS-staged KV tiles, KV split 4-way across blocks.
// Scores arrive in log2 domain (Q pre-scaled); softmax uses exp2.
// ---------------------------------------------------------------------------
__global__ __launch_bounds__(256, 2) void attn_kernel(
    const _Float16* __restrict__ qfrag, const char* __restrict__ kimg,
    const char* __restrict__ vimg, short* __restrict__ pacc,
    float* __restrict__ pml) {
  __shared__ __align__(16) char smem[2][STAGE_B];   // 32 KB
  const int tid = threadIdx.x, wave = tid >> 6, lane = tid & 63;
  const int g = lane >> 4, qr = lane & 15;

  const int i = blockIdx.x;
  const int stream = i & 15;            // blocks sharing a KV stream land on one XCD
  const int b = stream >> 2, quarter = stream & 3;
  const int qg = i >> 4;                // 0..31 (128 q-rows each)

  // Q fragments for this wave's two 16-row tiles.
  const int t0 = b * 256 + qg * 8 + wave * 2;
  half8 qf[2][4];
#pragma unroll
  for (int qs = 0; qs < 2; ++qs)
#pragma unroll
    for (int c4 = 0; c4 < 4; ++c4)
      qf[qs][c4] = *(const half8*)(qfrag +
          ((size_t)((t0 + qs) * 4 + c4) * 64 + lane) * 8);

  const char* kb_g = kimg + ((size_t)b * NTILE + quarter * 32) * KTILE_B;
  const char* vb_g = vimg + ((size_t)b * NTILE + quarter * 32) * VTILE_B;

  auto stage = [&](int t, char* buf) {
    const char* ks = kb_g + (size_t)t * KTILE_B;
    const char* vs = vb_g + (size_t)t * VTILE_B;
    gl_lds16(ks + tid * 16, buf + tid * 16);
    gl_lds16(ks + 4096 + tid * 16, buf + 4096 + tid * 16);
    gl_lds16(vs + tid * 16, buf + 8192 + tid * 16);
    gl_lds16(vs + 4096 + tid * 16, buf + 12288 + tid * 16);
  };

  f32x4 acc[2][8];
#pragma unroll
  for (int qs = 0; qs < 2; ++qs)
#pragma unroll
    for (int dt = 0; dt < 8; ++dt) acc[qs][dt] = (f32x4){0.f, 0.f, 0.f, 0.f};
  float m[2] = {-INFINITY, -INFINITY}, lsum[2] = {0.f, 0.f};

  stage(0, smem[0]);

  auto phase = [&](int t, char* cur, char* other, bool do_stage) {
    asm volatile("s_waitcnt vmcnt(0) lgkmcnt(0)" ::: "memory");
    __builtin_amdgcn_s_barrier();
    if (do_stage) stage(t + 1, other);

    // ---- S^T = K.Q^T (K frags shared across the wave's 2 q-tiles) --------
    f32x4 sA[2][2];
#pragma unroll
    for (int s = 0; s < 2; ++s) {
      half8 kf[4];
#pragma unroll
      for (int c4 = 0; c4 < 4; ++c4) {
        int slot = 4 * c4 + g;
        int slotp = (slot & 8) | ((slot ^ qr) & 7);
        kf[c4] = *(const half8*)(cur + (16 * s + qr) * 256 + slotp * 16);
      }
      __builtin_amdgcn_s_setprio(1);
#pragma unroll
      for (int qs = 0; qs < 2; ++qs) {
        f32x4 tac = (f32x4){0.f, 0.f, 0.f, 0.f};
#pragma unroll
        for (int c4 = 0; c4 < 4; ++c4)
          tac = __builtin_amdgcn_mfma_f32_16x16x32_f16(kf[c4], qf[qs][c4], tac, 0, 0, 0);
        sA[qs][s] = tac;
      }
      __builtin_amdgcn_s_setprio(0);
    }

    // ---- online softmax (log2 domain), per q-set --------------------------
    bf16x4 pf[2][2];
#pragma unroll
    for (int qs = 0; qs < 2; ++qs) {
      float tm = fmaxf(
          fmaxf(fmaxf(sA[qs][0][0], sA[qs][0][1]), fmaxf(sA[qs][0][2], sA[qs][0][3])),
          fmaxf(fmaxf(sA[qs][1][0], sA[qs][1][1]), fmaxf(sA[qs][1][2], sA[qs][1][3])));
      tm = fmaxf(tm, __shfl_xor(tm, 16, 64));
      tm = fmaxf(tm, __shfl_xor(tm, 32, 64));
      if (!__all(tm <= m[qs] + 8.0f)) {          // defer-max (p <= 2^8)
        float mn = fmaxf(m[qs], tm);
        float alpha = exp2f(m[qs] - mn);
        m[qs] = mn;
        lsum[qs] *= alpha;
        float af[4];
#pragma unroll
        for (int r = 0; r < 4; ++r) af[r] = __shfl(alpha, 4 * g + r, 64);
#pragma unroll
        for (int dt = 0; dt < 8; ++dt)
#pragma unroll
          for (int r = 0; r < 4; ++r) acc[qs][dt][r] *= af[r];
      }
      float p[8], ps = 0.f;
#pragma unroll
      for (int e = 0; e < 8; ++e) {
        p[e] = exp2f(sA[qs][e >> 2][e & 3] - m[qs]);
        ps += p[e];
      }
      ps += __shfl_xor(ps, 16, 64);
      ps += __shfl_xor(ps, 32, 64);
      lsum[qs] += ps;
#pragma unroll
      for (int r = 0; r < 4; ++r) { pf[qs][0][r] = f2bf(p[r]); pf[qs][1][r] = f2bf(p[4 + r]); }
    }

    // ---- PV: conflict-free V reads ([(k>>2)][d][k&3] image) ---------------
    const char* vb = cur + KTILE_B;
#pragma unroll
    for (int dt = 0; dt < 8; ++dt) {
      bf16x4 v0 = *(const bf16x4*)(vb + g * 1024 + dt * 128 + qr * 8);
      bf16x4 v1 = *(const bf16x4*)(vb + 4096 + g * 1024 + dt * 128 + qr * 8);
      __builtin_amdgcn_s_setprio(1);
#pragma unroll
      for (int qs = 0; qs < 2; ++qs) {
        acc[qs][dt] = __builtin_amdgcn_mfma_f32_16x16x16bf16_1k(pf[qs][0], v0, acc[qs][dt], 0, 0, 0);
        acc[qs][dt] = __builtin_amdgcn_mfma_f32_16x16x16bf16_1k(pf[qs][1], v1, acc[qs][dt], 0, 0, 0);
      }
      __builtin_amdgcn_s_setprio(0);
    }
  };

  for (int it = 0; it < 16; ++it) {
    phase(2 * it,     smem[0], smem[1], true);
    phase(2 * it + 1, smem[1], smem[0], 2 * it + 2 < 32);
  }

  // ---- store partials (bf16) ---------------------------------------------
  const int lrow0 = qg * 128 + wave * 32;
#pragma unroll
  for (int qs = 0; qs < 2; ++qs) {
#pragma unroll
    for (int dt = 0; dt < 8; ++dt)
#pragma unroll
      for (int r = 0; r < 4; ++r) {
        int grow = b * SEQ + lrow0 + qs * 16 + 4 * g + r;
        pacc[((size_t)quarter * NROWS + grow) * CDIM + 16 * dt + qr] =
            f2bf(acc[qs][dt][r]);
      }
    if (g == 0) {
      int grow = b * SEQ + lrow0 + qs * 16 + qr;
      pml[((size_t)quarter * NROWS + grow) * 2 + 0] = m[qs];
      pml[((size_t)quarter * NROWS + grow) * 2 + 1] = lsum[qs];
    }
  }
}

// ---------------------------------------------------------------------------
// Kernel 3: combine the four KV-quarter partials (log2-domain stats).
// ---------------------------------------------------------------------------
__global__ __launch_bounds__(256) void combine_kernel(
    const short* __restrict__ pacc, const float* __restrict__ pml,
    float* __restrict__ out) {
  int idx = blockIdx.x * 256 + threadIdx.x;   // NROWS*16 threads
  int row = idx >> 4, c8 = idx & 15;
  float mm[4], ll[4];
  float M = -INFINITY;
#pragma unroll
  for (int h = 0; h < 4; ++h) {
    mm[h] = pml[((size_t)h * NROWS + row) * 2 + 0];
    ll[h] = pml[((size_t)h * NROWS + row) * 2 + 1];
    M = fmaxf(M, mm[h]);
  }
  float o[8];
#pragma unroll
  for (int j = 0; j < 8; ++j) o[j] = 0.f;
  float wl = 0.f;
#pragma unroll
  for (int h = 0; h < 4; ++h) {
    float w = exp2f(mm[h] - M);
    wl += w * ll[h];
    bf16x8 a = ((const bf16x8*)pacc)[((size_t)h * NROWS + row) * 16 + c8];
#pragma unroll
    for (int j = 0; j < 8; ++j) o[j] += w * bf2f(a[j]);
  }
  float inv = 1.0f / wl;
  f32x4 o0 = {o[0] * inv, o[1] * inv, o[2] * inv, o[3] * inv};
  f32x4 o1 = {o[4] * inv, o[5] * inv, o[6] * inv, o[7] * inv};
  ((f32x4*)out)[(size_t)row * 32 + c8 * 2 + 0] = o0;
  ((f32x4*)out)[(size_t)row * 32 + c8 * 2 + 1] = o1;
}

// ---------------------------------------------------------------------------
extern "C" void kernel_launch(void* const* d_in, const int* in_sizes, int n_in,
                              void* d_out, int out_size, void* d_ws, size_t ws_size,
                              hipStream_t stream) {
  const float* x  = (const float*)d_in[0];
  const float* Wq = (const float*)d_in[1];
  const float* bq = (const float*)d_in[2];
  const float* Wk = (const float*)d_in[3];
  const float* bk = (const float*)d_in[4];
  const float* Wv = (const float*)d_in[5];
  const float* bv = (const float*)d_in[6];
  float* out = (float*)d_out;

  // Workspace layout (~28.9 MB)
  char* ws = (char*)d_ws;
  _Float16* qfrag = (_Float16*)(ws);                       // 4 MB
  char*     kimg  = ws + (4u << 20);                       // 4 MB
  char*     vimg  = ws + (8u << 20);                       // 4 MB
  _Float16* wfrag = (_Float16*)(ws + (12u << 20));         // 96 KB
  short*    pacc  = (short*)(ws + (12u << 20) + (256u << 10));  // 16 MB
  float*    pml   = (float*)(ws + (28u << 20) + (512u << 10));  // 512 KB

  wprep_kernel<<<dim3(64, 3), 256, 0, stream>>>(Wq, Wk, Wv, wfrag);
  proj_kernel<<<NROWS / 64, 256, 0, stream>>>(x, wfrag, bq, bk, bv,
                                              qfrag, (_Float16*)kimg, (short*)vimg);
  attn_kernel<<<512, 256, 0, stream>>>(qfrag, kimg, vimg, pacc, pml);
  combine_kernel<<<NROWS * 16 / 256, 256, 0, stream>>>(pacc, pml, out);
}